// Round 6
// baseline (277.274 us; speedup 1.0000x reference)
//
#include <hip/hip_runtime.h>

// EmbeddingCRF: feats = emb[sentence] @ W^T; CRF forward (LSE), gold score,
// Viterbi decode. Parallel-in-time via 12x12 semiring transfer matrices.
// R7: grid.sync ~31us -> ordinary dispatches are the cheap barrier (~6us).
// R8/R9: 128-step serial scans cost ~0.4us/step (broadcast+reduce chain, not
// loads — R9's LDS staging only dropped 78->56us). Serial DEPTH is what
// matters: R7's ≤16-step chains were right. R10: restore the 3-level tree
// inside ONE middle kernel (k_midT, 1 block): stage SMV+SMF to LDS; fold2 as
// 16x16-lane column-parallel groups (depth 16); hyper scans (depth 8); 
// expandA (depth 15) -> SBV/SSFX. Max chain 39 steps. Dead PF/SMVT writes
// removed from pass1f. 4 dispatches.

#define LSEQ    32768
#define NTAGS   14
#define R       12
#define T_START 12
#define T_STOP  13
#define EMBD    300
#define CCH     2048  // chunks
#define SCH     16    // steps per chunk
#define NSUP    128   // supers (16 chunks each)
#define NHYP    8     // hypers (16 supers each)

// ws layout (float offsets)
#define OFF_FEATS 0         // [L][12]
#define OFF_EXPF  393216    // [L][12]
#define OFF_FMAX  786432    // [L]
#define OFF_PF    819200    // (dead since R10; region kept: off-end prefetch target)
#define OFF_PV    1114112   // [2048][n][p] max-plus chunk mats
#define OFF_PVC   1409024   // [2048][p][n] transposed
#define OFF_SMV   1753104   // [128][n][p]
#define OFF_SMVT  1771536   // (dead since R10)
#define OFF_SMF   1789968   // [128][n][p]
#define OFF_SBV   1811856   // [128][12]
#define OFF_SSFX  1813392   // [128][12]
#define OFF_GOLDP 1815120   // [2048] per-block gold partials

__device__ __forceinline__ void load12(const float* __restrict__ p, float* r) {
  const float4* p4 = (const float4*)p;
  float4 a = p4[0], b = p4[1], c = p4[2];
  r[0]=a.x; r[1]=a.y; r[2]=a.z; r[3]=a.w;
  r[4]=b.x; r[5]=b.y; r[6]=b.z; r[7]=b.w;
  r[8]=c.x; r[9]=c.y; r[10]=c.z; r[11]=c.w;
}

__device__ __forceinline__ void lds12(const float* p, float* r) {
  const float4* p4 = (const float4*)p;
  float4 a = p4[0], b = p4[1], c = p4[2];
  r[0]=a.x; r[1]=a.y; r[2]=a.z; r[3]=a.w;
  r[4]=b.x; r[5]=b.y; r[6]=b.z; r[7]=b.w;
  r[8]=c.x; r[9]=c.y; r[10]=c.z; r[11]=c.w;
}

// ---------------- K1: feats + expfeat + featmax + gold partials -------------
__global__ __launch_bounds__(256) void k_feats(
    const int* __restrict__ sentence, const int* __restrict__ tags,
    const float* __restrict__ emb, const float* __restrict__ W,
    const float* __restrict__ trans, float* __restrict__ ws)
{
  __shared__ float Wl[NTAGS * EMBD];
  __shared__ float gacc;
  for (int i = threadIdx.x; i < NTAGS * EMBD; i += 256) Wl[i] = W[i];
  if (threadIdx.x == 0) gacc = 0.f;
  __syncthreads();

  int grp = threadIdx.x >> 4;
  int g   = threadIdx.x & 15;
  int pos = blockIdx.x * 16 + grp;
  int row = sentence[pos];

  float acc = 0.f;
  if (g < R) {
    const float4* e4 = (const float4*)(emb + (size_t)row * EMBD);
    const float4* w4 = (const float4*)(Wl + g * EMBD);
    #pragma unroll 5
    for (int i = 0; i < EMBD / 4; ++i) {
      float4 a = e4[i]; float4 b = w4[i];
      acc += a.x*b.x + a.y*b.y + a.z*b.z + a.w*b.w;
    }
  }
  float feat = (g < R) ? acc : -3.0e38f;
  float mx = feat;
  #pragma unroll
  for (int off = 1; off < 16; off <<= 1)
    mx = fmaxf(mx, __shfl_xor(mx, off, 16));

  if (g < R) {
    ws[OFF_FEATS + pos * 12 + g] = feat;
    ws[OFF_EXPF  + pos * 12 + g] = __expf(feat - mx);
  }
  if (g == 0) ws[OFF_FMAX + pos] = mx;

  int tg = tags[pos];
  if (g == tg) {
    int prev = (pos == 0) ? T_START : tags[pos - 1];
    float gc = feat + trans[tg * NTAGS + prev];
    if (pos == LSEQ - 1) gc += trans[T_STOP * NTAGS + tg];
    atomicAdd(&gacc, gc);
  }
  __syncthreads();
  if (threadIdx.x == 0) ws[OFF_GOLDP + blockIdx.x] = gacc;
}

// ---------------- K2: chunk transfer matrices + in-block fold1 --------------
// grid 256 = 128 supers x 2 semirings (sem = bid>>7: 0 LSE, 1 viterbi).
// block 256 thr = 16 chunks x 16 cols. Phase A: per-thread 16-step chunk
// scan; viterbi chunk mats -> global (PV+PVC) AND LDS; LSE mats LDS-only
// (PF was dead). Phase B: threads 0..143 fold 16 LDS mats -> super mat
// (SMF / SMV; SMVT dead). __launch_bounds__(256,1): no spill (R5 trap).
__global__ __launch_bounds__(256, 1) void k_pass1f(
    const float* __restrict__ trans, float* __restrict__ ws)
{
  __shared__ float Msh[16 * 144];   // 9.2 KB
  __shared__ float Vl[144];

  int tid = threadIdx.x;
  int sem = blockIdx.x >> 7;
  int s   = blockIdx.x & 127;
  int q = tid >> 4;
  int p = tid & 15;
  int c = s * 16 + q;
  int t0 = (c == 0) ? 1 : c * SCH;
  int t1 = c * SCH + SCH;
  bool act = (p < R);

  float Treg[R][R];

  if (sem == 0) {
    // LSE semiring (prob domain with exponent rescaling)
    #pragma unroll
    for (int n = 0; n < R; ++n)
      #pragma unroll
      for (int m = 0; m < R; ++m)
        Treg[n][m] = __expf(trans[n * NTAGS + m]);

    float E[R];
    #pragma unroll
    for (int m = 0; m < R; ++m) E[m] = (m == p) ? 1.f : 0.f;
    int kacc = 0;
    float sfeat = 0.f;

    float ef[R];
    load12(ws + OFF_EXPF + t0 * 12, ef);
    float fm = ws[OFF_FMAX + t0];

    for (int t = t0; t < t1; ++t) {
      float efn[R];
      load12(ws + OFF_EXPF + (t + 1) * 12, efn);   // off-end lands in FMAX: safe
      float fmn = ws[OFF_FMAX + t + 1];            // off-end lands in PF: safe
      sfeat += fm;
      float NE[R];
      #pragma unroll
      for (int n = 0; n < R; ++n) {
        float sv = Treg[n][0] * E[0];
        #pragma unroll
        for (int m = 1; m < R; ++m) sv = fmaf(Treg[n][m], E[m], sv);
        NE[n] = sv * ef[n];
      }
      #pragma unroll
      for (int n = 0; n < R; ++n) E[n] = NE[n];
      if ((t & 7) == 7) {
        float mx = E[0];
        #pragma unroll
        for (int n = 1; n < R; ++n) mx = fmaxf(mx, E[n]);
        if (mx > 0.f) {
          int k = ((__float_as_int(mx) >> 23) & 0xFF) - 127;
          float sc = __int_as_float((127 - k) << 23);
          #pragma unroll
          for (int n = 0; n < R; ++n) E[n] *= sc;
          kacc += k;
        }
      }
      #pragma unroll
      for (int n = 0; n < R; ++n) ef[n] = efn[n];
      fm = fmn;
    }
    if (act) {
      float base = (float)kacc * 0.6931471805599453f + sfeat;
      #pragma unroll
      for (int n = 0; n < R; ++n) {
        float v = (E[n] > 0.f) ? (__logf(E[n]) + base) : -1.0e30f;
        Msh[q * 144 + n * 12 + p] = v;
      }
    }
  } else {
    // max-plus semiring
    #pragma unroll
    for (int n = 0; n < R; ++n)
      #pragma unroll
      for (int m = 0; m < R; ++m)
        Treg[n][m] = trans[n * NTAGS + m];

    float V[R];
    #pragma unroll
    for (int m = 0; m < R; ++m) V[m] = (m == p) ? 0.f : -1.0e30f;

    float fr[R];
    load12(ws + OFF_FEATS + t0 * 12, fr);

    for (int t = t0; t < t1; ++t) {
      float frn[R];
      load12(ws + OFF_FEATS + (t + 1) * 12, frn);  // off-end lands in EXPF: safe
      float NV[R];
      #pragma unroll
      for (int n = 0; n < R; ++n) {
        float b = Treg[n][0] + V[0];
        #pragma unroll
        for (int m = 1; m < R; ++m) b = fmaxf(b, Treg[n][m] + V[m]);
        NV[n] = b + fr[n];
      }
      #pragma unroll
      for (int n = 0; n < R; ++n) { V[n] = NV[n]; fr[n] = frn[n]; }
    }
    if (act) {
      #pragma unroll
      for (int n = 0; n < R; ++n) {
        ws[OFF_PV  + c * 144 + n * 12 + p] = V[n];
        ws[OFF_PVC + c * 144 + p * 12 + n] = V[n];
        Msh[q * 144 + n * 12 + p] = V[n];
      }
    }
  }
  __syncthreads();

  // Phase B: fold 16 chunk mats (LDS) -> super mat
  {
    int l = tid;
    bool fa = (l < 144);
    int fn = l / 12;
    int fp = l - fn * 12;
    float V = (fa && fn == fp) ? 0.f : -1.0e30f;

    for (int j = 0; j < 16; ++j) {
      if (fa) Vl[l] = V;
      __syncthreads();
      if (fa) {
        const float* M = Msh + j * 144 + fn * 12;
        if (sem == 1) {
          float best = -3.0e38f;
          #pragma unroll
          for (int m = 0; m < R; ++m)
            best = fmaxf(best, M[m] + Vl[m * 12 + fp]);
          V = best;
        } else {
          float cand[R]; float mx = -3.0e38f;
          #pragma unroll
          for (int m = 0; m < R; ++m) {
            cand[m] = M[m] + Vl[m * 12 + fp];
            mx = fmaxf(mx, cand[m]);
          }
          float sum = 0.f;
          #pragma unroll
          for (int m = 0; m < R; ++m) sum += __expf(cand[m] - mx);
          V = mx + __logf(sum);
        }
      }
      __syncthreads();
    }
    if (fa) {
      if (sem == 1) ws[OFF_SMV + s * 144 + fn * 12 + fp] = V;
      else          ws[OFF_SMF + s * 144 + fn * 12 + fp] = V;
    }
  }
}

// ---------------- K_midT: 3-level middle stage in one block ----------------
// P0 stage SMV+SMF -> LDS (144KB) + gold partial sums.
// P1 fold2: 16 groups x 16 lanes (waves0-1 viterbi, waves2-3 LSE); lane p
//    holds column p of the running 12x12 product in registers; depth 16.
// P2 hyper scans (depth 8, LDS broadcast) -> out[1], lse, gold -> out[0].
// P3 expandA: 16 tasks x 15-step scans over LDS SMV (transpose = strided
//    reads) -> SBV/SSFX global for k_expBdec.
__global__ __launch_bounds__(256) void k_midT(
    const float* __restrict__ trans, float* __restrict__ ws,
    float* __restrict__ out)
{
  __shared__ float Lsh[NSUP * 144 * 2 + NHYP * 144 * 2];  // 156672 B
  __shared__ float hbv_sh[NHYP][12];
  __shared__ float hsfx_sh[NHYP][12];
  __shared__ float Vm[3][16];
  __shared__ float VexA[16][16];
  __shared__ float gpart[64];
  __shared__ float gold_sh, lse_sh;

  float* lsmv = Lsh;                         // [128][144]
  float* lsmf = Lsh + NSUP * 144;            // [128][144]
  float* hmv  = Lsh + NSUP * 144 * 2;        // [8][144]
  float* hmf  = hmv + NHYP * 144;            // [8][144]

  int tid  = threadIdx.x;
  int wid  = tid >> 6;
  int lane = tid & 63;

  // ===== P0: stage + gold partial sums =====
  {
    const float4* a4 = (const float4*)(ws + OFF_SMV);
    const float4* b4 = (const float4*)(ws + OFF_SMF);
    float4* d0 = (float4*)lsmv;
    float4* d1 = (float4*)lsmf;
    for (int i = tid; i < NSUP * 36; i += 256) { d0[i] = a4[i]; d1[i] = b4[i]; }
    if (wid == 3) {
      float sg = 0.f;
      for (int i = lane; i < CCH; i += 64) sg += ws[OFF_GOLDP + i];
      gpart[lane] = sg;
    }
  }
  __syncthreads();

  // ===== P1: fold 16 supers -> hyper mats (column-parallel groups) =====
  {
    int t    = tid >> 4;      // task 0..15
    int p    = tid & 15;      // column
    int kind = t >> 3;        // 0 = viterbi (waves 0-1), 1 = LSE (waves 2-3)
    int h    = t & 7;
    float A[R];
    #pragma unroll
    for (int m = 0; m < R; ++m) A[m] = (m == p) ? 0.f : -1.0e30f;
    const float* base = kind ? lsmf : lsmv;
    for (int j = 0; j < 16; ++j) {
      const float* M = base + (h * 16 + j) * 144;
      float NA[R];
      if (kind == 0) {
        #pragma unroll
        for (int n = 0; n < R; ++n) {
          float b = M[n * 12] + A[0];
          #pragma unroll
          for (int m = 1; m < R; ++m) b = fmaxf(b, M[n * 12 + m] + A[m]);
          NA[n] = b;
        }
      } else {
        #pragma unroll
        for (int n = 0; n < R; ++n) {
          float cand[R]; float mx = -3.0e38f;
          #pragma unroll
          for (int m = 0; m < R; ++m) {
            cand[m] = M[n * 12 + m] + A[m];
            mx = fmaxf(mx, cand[m]);
          }
          float sum = 0.f;
          #pragma unroll
          for (int m = 0; m < R; ++m) sum += __expf(cand[m] - mx);
          NA[n] = mx + __logf(sum);
        }
      }
      #pragma unroll
      for (int n = 0; n < R; ++n) A[n] = NA[n];
    }
    if (p < R) {
      float* dst = kind ? (hmf + h * 144) : (hmv + h * 144);
      #pragma unroll
      for (int n = 0; n < R; ++n) dst[n * 12 + p] = A[n];
    }
  }
  __syncthreads();

  // ===== P2: hyper-level scans (depth 8) + reductions =====
  {
    int n = lane;
    bool act = (n < R);
    if (wid == 0) {
      // Viterbi forward -> hbv_sh + out[1]
      float x = -3.0e38f;
      if (act) {
        x = trans[n * NTAGS + T_START] + ws[OFF_FEATS + n];
        hbv_sh[0][n] = x;
        Vm[0][n] = x;
      }
      for (int h = 0; h < NHYP; ++h) {
        float row[R], v[R];
        if (act) lds12(hmv + h * 144 + n * 12, row);
        lds12(Vm[0], v);
        if (act) {
          float nx = row[0] + v[0];
          #pragma unroll
          for (int m = 1; m < R; ++m) nx = fmaxf(nx, row[m] + v[m]);
          if (h < NHYP - 1) hbv_sh[h + 1][n] = nx;
          Vm[0][n] = nx;
        }
      }
      float t2 = act ? (Vm[0][n] + trans[T_STOP * NTAGS + n]) : -3.0e38f;
      #pragma unroll
      for (int off = 1; off < 16; off <<= 1)
        t2 = fmaxf(t2, __shfl_xor(t2, off, 16));
      if (lane == 0) out[1] = t2;
    } else if (wid == 1) {
      // Viterbi suffix -> hsfx_sh (HMVT row n = strided hmv reads)
      float x = -3.0e38f;
      if (act) {
        x = trans[T_STOP * NTAGS + n];
        hsfx_sh[NHYP - 1][n] = x;
        Vm[1][n] = x;
      }
      for (int h = NHYP - 1; h >= 1; --h) {
        float row[R], v[R];
        if (act) {
          #pragma unroll
          for (int m = 0; m < R; ++m) row[m] = hmv[h * 144 + m * 12 + n];
        }
        lds12(Vm[1], v);
        if (act) {
          float nx = row[0] + v[0];
          #pragma unroll
          for (int m = 1; m < R; ++m) nx = fmaxf(nx, row[m] + v[m]);
          hsfx_sh[h - 1][n] = nx;
          Vm[1][n] = nx;
        }
      }
    } else if (wid == 2) {
      // LSE forward -> lse_sh
      float x = -3.0e38f;
      if (act) {
        x = trans[n * NTAGS + T_START] + ws[OFF_FEATS + n];
        Vm[2][n] = x;
      }
      for (int h = 0; h < NHYP; ++h) {
        float row[R], v[R];
        if (act) lds12(hmf + h * 144 + n * 12, row);
        lds12(Vm[2], v);
        if (act) {
          float tv[R]; float mx = -3.0e38f;
          #pragma unroll
          for (int m = 0; m < R; ++m) { tv[m] = row[m] + v[m]; mx = fmaxf(mx, tv[m]); }
          float sum = 0.f;
          #pragma unroll
          for (int m = 0; m < R; ++m) sum += __expf(tv[m] - mx);
          Vm[2][n] = mx + __logf(sum);
        }
      }
      float t2 = act ? (Vm[2][n] + trans[T_STOP * NTAGS + n]) : -3.0e38f;
      float mx = t2;
      #pragma unroll
      for (int off = 1; off < 16; off <<= 1)
        mx = fmaxf(mx, __shfl_xor(mx, off, 16));
      float e = act ? __expf(t2 - mx) : 0.f;
      #pragma unroll
      for (int off = 1; off < 16; off <<= 1)
        e += __shfl_xor(e, off, 16);
      if (lane == 0) lse_sh = mx + __logf(e);
    } else {
      // gold reduce
      float sg = gpart[lane];
      #pragma unroll
      for (int off = 1; off < 64; off <<= 1) sg += __shfl_xor(sg, off);
      if (lane == 0) gold_sh = sg;
    }
  }
  __syncthreads();
  if (tid == 0) out[0] = lse_sh - gold_sh;

  // ===== P3: expandA — hyper vectors -> super vectors (SBV/SSFX) =====
  {
    int dir  = tid >> 7;          // waves 0-1: fwd, waves 2-3: suffix
    int task = tid >> 4;          // 0..15
    int h    = task & 7;
    int g    = tid & 15;
    bool act = (g < R);

    if (dir == 0) {
      float x = -3.0e38f;
      if (act) {
        x = hbv_sh[h][g];
        ws[OFF_SBV + (h * 16) * 12 + g] = x;
        VexA[task][g] = x;
      }
      for (int j = 0; j < 15; ++j) {
        int s = h * 16 + j;
        float row[R], v[R];
        if (act) lds12(lsmv + s * 144 + g * 12, row);
        lds12(VexA[task], v);
        if (act) {
          float nx = row[0] + v[0];
          #pragma unroll
          for (int m = 1; m < R; ++m) nx = fmaxf(nx, row[m] + v[m]);
          ws[OFF_SBV + (s + 1) * 12 + g] = nx;
          VexA[task][g] = nx;
        }
      }
    } else {
      float x = -3.0e38f;
      if (act) {
        x = hsfx_sh[h][g];
        ws[OFF_SSFX + (h * 16 + 15) * 12 + g] = x;
        VexA[task][g] = x;
      }
      for (int j = 15; j >= 1; --j) {
        int s = h * 16 + j;
        float row[R], v[R];
        if (act) {
          #pragma unroll
          for (int m = 0; m < R; ++m) row[m] = lsmv[s * 144 + m * 12 + g];
        }
        lds12(VexA[task], v);
        if (act) {
          float nx = row[0] + v[0];
          #pragma unroll
          for (int m = 1; m < R; ++m) nx = fmaxf(nx, row[m] + v[m]);
          ws[OFF_SSFX + (s - 1) * 12 + g] = nx;
          VexA[task][g] = nx;
        }
      }
    }
  }
}

// ---------------- K_expBdec: per-super expandB scans + decode ---------------
// 128 blocks x 256 thr. Phase A: wave0 lanes 0-15 compute BV for the super's
// 16 chunks (LDS); wave1 lanes 0-15 compute SFX. Phase B: decode 16 chunks
// x 16 lanes. No BV/SFX global round-trip.
__global__ __launch_bounds__(256) void k_expBdec(
    const float* __restrict__ trans, const float* __restrict__ ws,
    float* __restrict__ out)
{
  __shared__ float bv_sh[SCH][12];
  __shared__ float sfx_sh[SCH][12];
  __shared__ float Vdec[SCH][16];
  __shared__ unsigned char bpd[SCH][SCH][16];

  int tid = threadIdx.x;
  int s   = blockIdx.x;

  if (tid < 16) {
    // dir0: BV scan over PV mats
    int g = tid; bool act = (g < R);
    float x = -3.0e38f;
    if (act) { x = ws[OFF_SBV + s * 12 + g]; bv_sh[0][g] = x; }
    float row[R], rown[R];
    if (act) load12(ws + OFF_PV + (s * 16) * 144 + g * 12, row);
    for (int j = 0; j < 15; ++j) {
      if (act) load12(ws + OFF_PV + (s * 16 + j + 1) * 144 + g * 12, rown);
      float v[R];
      lds12(bv_sh[j], v);
      if (act) {
        float nx = row[0] + v[0];
        #pragma unroll
        for (int m = 1; m < R; ++m) nx = fmaxf(nx, row[m] + v[m]);
        bv_sh[j + 1][g] = nx;
        #pragma unroll
        for (int m = 0; m < R; ++m) row[m] = rown[m];
      }
    }
  } else if (tid >= 64 && tid < 80) {
    // dir1: SFX scan over PVC mats
    int g = tid - 64; bool act = (g < R);
    float x = -3.0e38f;
    if (act) { x = ws[OFF_SSFX + s * 12 + g]; sfx_sh[SCH - 1][g] = x; }
    float row[R], rown[R];
    if (act) load12(ws + OFF_PVC + (s * 16 + 15) * 144 + g * 12, row);
    for (int j = 15; j >= 1; --j) {
      if (act) load12(ws + OFF_PVC + (s * 16 + j - 1) * 144 + g * 12, rown);
      float v[R];
      lds12(sfx_sh[j], v);
      if (act) {
        float nx = row[0] + v[0];
        #pragma unroll
        for (int m = 1; m < R; ++m) nx = fmaxf(nx, row[m] + v[m]);
        sfx_sh[j - 1][g] = nx;
        #pragma unroll
        for (int m = 0; m < R; ++m) row[m] = rown[m];
      }
    }
  }
  __syncthreads();

  // decode: 16 chunks x 16 lanes
  {
    int q = tid >> 4;
    int g = tid & 15;
    int c = s * 16 + q;
    int t0 = (c == 0) ? 1 : c * SCH;
    int t1 = c * SCH + SCH;
    bool act = (g < R);

    float treg[R];
    #pragma unroll
    for (int m = 0; m < R; ++m) treg[m] = act ? trans[g * NTAGS + m] : 0.f;

    float fv = act ? bv_sh[q][g] : -3.0e38f;
    Vdec[q][g] = fv;
    float fc = ws[OFF_FEATS + t0 * 12 + g];

    for (int t = t0; t < t1; ++t) {
      float fn = ws[OFF_FEATS + (t + 1) * 12 + g];   // off-end: EXPF, unused
      float v[R];
      lds12(Vdec[q], v);
      float best = -3.0e38f; int bi = 0;
      #pragma unroll
      for (int m = 0; m < R; ++m) {
        float cand = treg[m] + v[m];
        if (cand > best) { best = cand; bi = m; }
      }
      float nfv = best + fc;
      if (act) {
        bpd[q][t - t0][g] = (unsigned char)bi;
        Vdec[q][g] = nfv;
      }
      fc = fn;
    }

    Vdec[q][g] = act ? (Vdec[q][g] + sfx_sh[q][g]) : -3.0e38f;

    if (g == 0) {
      float best = Vdec[q][0]; int idx = 0;
      #pragma unroll
      for (int m = 1; m < R; ++m) {
        float v = Vdec[q][m];
        if (v > best) { best = v; idx = m; }
      }
      int cur = idx;
      int len = t1 - t0;
      out[2 + t0 + len - 1] = (float)cur;
      for (int tt = len - 1; tt >= 1; --tt) {
        cur = bpd[q][tt][cur];
        out[2 + t0 + tt - 1] = (float)cur;
      }
      if (c == 0) {
        cur = bpd[q][0][cur];
        out[2 + 0] = (float)cur;
      }
    }
  }
}

extern "C" void kernel_launch(void* const* d_in, const int* in_sizes, int n_in,
                              void* d_out, int out_size, void* d_ws, size_t ws_size,
                              hipStream_t stream) {
  (void)in_sizes; (void)n_in; (void)out_size; (void)ws_size;
  const int*   sentence = (const int*)d_in[0];
  const int*   tags     = (const int*)d_in[1];
  const float* emb      = (const float*)d_in[2];
  const float* W        = (const float*)d_in[3];
  const float* trans    = (const float*)d_in[4];
  float* ws  = (float*)d_ws;
  float* out = (float*)d_out;

  k_feats<<<LSEQ / 16, 256, 0, stream>>>(sentence, tags, emb, W, trans, ws);
  k_pass1f<<<NSUP * 2, 256, 0, stream>>>(trans, ws);
  k_midT<<<1, 256, 0, stream>>>(trans, ws, out);
  k_expBdec<<<NSUP, 256, 0, stream>>>(trans, ws, out);
}

// Round 7
// 240.089 us; speedup vs baseline: 1.1549x; 1.1549x over previous
//
#include <hip/hip_runtime.h>

// EmbeddingCRF: feats = emb[sentence] @ W^T; CRF forward (LSE), gold score,
// Viterbi decode. Parallel-in-time via 12x12 semiring transfer matrices.
// Calibrated costs (R5-R10): grid.sync ~31us (dead end); dispatch ~6us;
// serial semiring step ~0.4us regardless of LDS/global residency (R8 vs R9);
// single-block latency stacking ~70us (R10's k_midT — reverted).
// R11: recombine the measured-best pieces. 5 dispatches:
//   k_feats | k_pass1f (fold1 fused into pass1 — isolated ~20us win vs
//   pass1+foldS1, kills the 2.4MB cross-XCD PV/PF round-trip; PF write
//   dropped, SMVT kept) | k_foldS fold2 (16 parallel blocks, LDS-staged) |
//   k_midexpA (R7 verbatim: depth-8 hyper scans + expandA in 1 block) |
//   k_expBdec (per-super BV/SFX scans + decode, LDS handoff).
// Max serial chain per level <= 16 steps; each level parallel across CUs.

#define LSEQ    32768
#define NTAGS   14
#define R       12
#define T_START 12
#define T_STOP  13
#define EMBD    300
#define CCH     2048  // chunks
#define SCH     16    // steps per chunk
#define NSUP    128   // supers (16 chunks each)
#define NHYP    8     // hypers (16 supers each)

// ws layout (float offsets)
#define OFF_FEATS 0         // [L][12]
#define OFF_EXPF  393216    // [L][12]
#define OFF_FMAX  786432    // [L]
#define OFF_PF    819200    // (dead region; off-end prefetch target only)
#define OFF_PV    1114112   // [2048][n][p] max-plus chunk mats
#define OFF_PVC   1409024   // [2048][p][n] transposed
#define OFF_SMV   1753104   // [128][n][p]
#define OFF_SMVT  1771536   // [128][p][n]
#define OFF_SMF   1789968   // [128][n][p]
#define OFF_HMV   1808400   // [8][n][p]
#define OFF_HMVT  1809552   // [8][p][n]
#define OFF_HMF   1810704   // [8][n][p]
#define OFF_SBV   1811856   // [128][12]
#define OFF_SSFX  1813392   // [128][12]
#define OFF_GOLDP 1815120   // [2048] per-block gold partials

__device__ __forceinline__ void load12(const float* __restrict__ p, float* r) {
  const float4* p4 = (const float4*)p;
  float4 a = p4[0], b = p4[1], c = p4[2];
  r[0]=a.x; r[1]=a.y; r[2]=a.z; r[3]=a.w;
  r[4]=b.x; r[5]=b.y; r[6]=b.z; r[7]=b.w;
  r[8]=c.x; r[9]=c.y; r[10]=c.z; r[11]=c.w;
}

__device__ __forceinline__ void lds12(const float* p, float* r) {
  const float4* p4 = (const float4*)p;
  float4 a = p4[0], b = p4[1], c = p4[2];
  r[0]=a.x; r[1]=a.y; r[2]=a.z; r[3]=a.w;
  r[4]=b.x; r[5]=b.y; r[6]=b.z; r[7]=b.w;
  r[8]=c.x; r[9]=c.y; r[10]=c.z; r[11]=c.w;
}

// ---------------- K1: feats + expfeat + featmax + gold partials -------------
__global__ __launch_bounds__(256) void k_feats(
    const int* __restrict__ sentence, const int* __restrict__ tags,
    const float* __restrict__ emb, const float* __restrict__ W,
    const float* __restrict__ trans, float* __restrict__ ws)
{
  __shared__ float Wl[NTAGS * EMBD];
  __shared__ float gacc;
  for (int i = threadIdx.x; i < NTAGS * EMBD; i += 256) Wl[i] = W[i];
  if (threadIdx.x == 0) gacc = 0.f;
  __syncthreads();

  int grp = threadIdx.x >> 4;
  int g   = threadIdx.x & 15;
  int pos = blockIdx.x * 16 + grp;
  int row = sentence[pos];

  float acc = 0.f;
  if (g < R) {
    const float4* e4 = (const float4*)(emb + (size_t)row * EMBD);
    const float4* w4 = (const float4*)(Wl + g * EMBD);
    #pragma unroll 5
    for (int i = 0; i < EMBD / 4; ++i) {
      float4 a = e4[i]; float4 b = w4[i];
      acc += a.x*b.x + a.y*b.y + a.z*b.z + a.w*b.w;
    }
  }
  float feat = (g < R) ? acc : -3.0e38f;
  float mx = feat;
  #pragma unroll
  for (int off = 1; off < 16; off <<= 1)
    mx = fmaxf(mx, __shfl_xor(mx, off, 16));

  if (g < R) {
    ws[OFF_FEATS + pos * 12 + g] = feat;
    ws[OFF_EXPF  + pos * 12 + g] = __expf(feat - mx);
  }
  if (g == 0) ws[OFF_FMAX + pos] = mx;

  int tg = tags[pos];
  if (g == tg) {
    int prev = (pos == 0) ? T_START : tags[pos - 1];
    float gc = feat + trans[tg * NTAGS + prev];
    if (pos == LSEQ - 1) gc += trans[T_STOP * NTAGS + tg];
    atomicAdd(&gacc, gc);
  }
  __syncthreads();
  if (threadIdx.x == 0) ws[OFF_GOLDP + blockIdx.x] = gacc;
}

// ---------------- K2: chunk transfer matrices + in-block fold1 --------------
// grid 256 = 128 supers x 2 semirings (sem = bid>>7: 0 LSE, 1 viterbi).
// block 256 thr = 16 chunks x 16 cols. Phase A: per-thread 16-step chunk
// scan; viterbi mats -> PV+PVC+LDS; LSE mats LDS-only (PF dead). Phase B:
// threads 0..143 fold 16 LDS mats -> super mat (SMF / SMV+SMVT).
// __launch_bounds__(256,1): allow ~200 VGPR, no spill (R5 trap).
__global__ __launch_bounds__(256, 1) void k_pass1f(
    const float* __restrict__ trans, float* __restrict__ ws)
{
  __shared__ float Msh[16 * 144];   // 9.2 KB
  __shared__ float Vl[144];

  int tid = threadIdx.x;
  int sem = blockIdx.x >> 7;
  int s   = blockIdx.x & 127;
  int q = tid >> 4;
  int p = tid & 15;
  int c = s * 16 + q;
  int t0 = (c == 0) ? 1 : c * SCH;
  int t1 = c * SCH + SCH;
  bool act = (p < R);

  float Treg[R][R];

  if (sem == 0) {
    // LSE semiring (prob domain with exponent rescaling)
    #pragma unroll
    for (int n = 0; n < R; ++n)
      #pragma unroll
      for (int m = 0; m < R; ++m)
        Treg[n][m] = __expf(trans[n * NTAGS + m]);

    float E[R];
    #pragma unroll
    for (int m = 0; m < R; ++m) E[m] = (m == p) ? 1.f : 0.f;
    int kacc = 0;
    float sfeat = 0.f;

    float ef[R];
    load12(ws + OFF_EXPF + t0 * 12, ef);
    float fm = ws[OFF_FMAX + t0];

    for (int t = t0; t < t1; ++t) {
      float efn[R];
      load12(ws + OFF_EXPF + (t + 1) * 12, efn);   // off-end lands in FMAX: safe
      float fmn = ws[OFF_FMAX + t + 1];            // off-end lands in PF: safe
      sfeat += fm;
      float NE[R];
      #pragma unroll
      for (int n = 0; n < R; ++n) {
        float sv = Treg[n][0] * E[0];
        #pragma unroll
        for (int m = 1; m < R; ++m) sv = fmaf(Treg[n][m], E[m], sv);
        NE[n] = sv * ef[n];
      }
      #pragma unroll
      for (int n = 0; n < R; ++n) E[n] = NE[n];
      if ((t & 7) == 7) {
        float mx = E[0];
        #pragma unroll
        for (int n = 1; n < R; ++n) mx = fmaxf(mx, E[n]);
        if (mx > 0.f) {
          int k = ((__float_as_int(mx) >> 23) & 0xFF) - 127;
          float sc = __int_as_float((127 - k) << 23);
          #pragma unroll
          for (int n = 0; n < R; ++n) E[n] *= sc;
          kacc += k;
        }
      }
      #pragma unroll
      for (int n = 0; n < R; ++n) ef[n] = efn[n];
      fm = fmn;
    }
    if (act) {
      float base = (float)kacc * 0.6931471805599453f + sfeat;
      #pragma unroll
      for (int n = 0; n < R; ++n) {
        float v = (E[n] > 0.f) ? (__logf(E[n]) + base) : -1.0e30f;
        Msh[q * 144 + n * 12 + p] = v;
      }
    }
  } else {
    // max-plus semiring
    #pragma unroll
    for (int n = 0; n < R; ++n)
      #pragma unroll
      for (int m = 0; m < R; ++m)
        Treg[n][m] = trans[n * NTAGS + m];

    float V[R];
    #pragma unroll
    for (int m = 0; m < R; ++m) V[m] = (m == p) ? 0.f : -1.0e30f;

    float fr[R];
    load12(ws + OFF_FEATS + t0 * 12, fr);

    for (int t = t0; t < t1; ++t) {
      float frn[R];
      load12(ws + OFF_FEATS + (t + 1) * 12, frn);  // off-end lands in EXPF: safe
      float NV[R];
      #pragma unroll
      for (int n = 0; n < R; ++n) {
        float b = Treg[n][0] + V[0];
        #pragma unroll
        for (int m = 1; m < R; ++m) b = fmaxf(b, Treg[n][m] + V[m]);
        NV[n] = b + fr[n];
      }
      #pragma unroll
      for (int n = 0; n < R; ++n) { V[n] = NV[n]; fr[n] = frn[n]; }
    }
    if (act) {
      #pragma unroll
      for (int n = 0; n < R; ++n) {
        ws[OFF_PV  + c * 144 + n * 12 + p] = V[n];
        ws[OFF_PVC + c * 144 + p * 12 + n] = V[n];
        Msh[q * 144 + n * 12 + p] = V[n];
      }
    }
  }
  __syncthreads();

  // Phase B: fold 16 chunk mats (LDS) -> super mat
  {
    int l = tid;
    bool fa = (l < 144);
    int fn = l / 12;
    int fp = l - fn * 12;
    float V = (fa && fn == fp) ? 0.f : -1.0e30f;

    for (int j = 0; j < 16; ++j) {
      if (fa) Vl[l] = V;
      __syncthreads();
      if (fa) {
        const float* M = Msh + j * 144 + fn * 12;
        if (sem == 1) {
          float best = -3.0e38f;
          #pragma unroll
          for (int m = 0; m < R; ++m)
            best = fmaxf(best, M[m] + Vl[m * 12 + fp]);
          V = best;
        } else {
          float cand[R]; float mx = -3.0e38f;
          #pragma unroll
          for (int m = 0; m < R; ++m) {
            cand[m] = M[m] + Vl[m * 12 + fp];
            mx = fmaxf(mx, cand[m]);
          }
          float sum = 0.f;
          #pragma unroll
          for (int m = 0; m < R; ++m) sum += __expf(cand[m] - mx);
          V = mx + __logf(sum);
        }
      }
      __syncthreads();
    }
    if (fa) {
      if (sem == 1) {
        ws[OFF_SMV  + s * 144 + fn * 12 + fp] = V;
        ws[OFF_SMVT + s * 144 + fp * 12 + fn] = V;
      } else {
        ws[OFF_SMF + s * 144 + fn * 12 + fp] = V;
      }
    }
  }
}

// ---------------- K_foldS: 16-way semiring fold, LDS-staged (fold2) ---------
// grid = NHYP*2; blockIdx&1: 0 = viterbi (SMV -> HMV+HMVT), 1 = LSE.
__global__ __launch_bounds__(192) void k_foldS(
    float* __restrict__ ws, int srcV, int srcF, int dstV, int dstVT, int dstF)
{
  __shared__ float Msh[16 * 144];   // 9.2 KB
  __shared__ float Vl[144];
  int s   = blockIdx.x >> 1;
  int sem = blockIdx.x & 1;
  int l = threadIdx.x;
  bool act = (l < 144);
  int n = l / 12;
  int p = l - n * 12;
  int base = sem ? srcF : srcV;

  // stage 16 mats = 2304 floats = 576 float4; 192 thr x 3
  const float4* src4 = (const float4*)(ws + base + s * (16 * 144));
  float4* d4 = (float4*)Msh;
  #pragma unroll
  for (int i = 0; i < 3; ++i) d4[l + i * 192] = src4[l + i * 192];

  float V = (act && n == p) ? 0.f : -1.0e30f;
  __syncthreads();

  for (int j = 0; j < 16; ++j) {
    if (act) Vl[l] = V;
    __syncthreads();
    if (act) {
      const float* M = Msh + j * 144 + n * 12;
      if (sem == 0) {
        float best = -3.0e38f;
        #pragma unroll
        for (int m = 0; m < R; ++m)
          best = fmaxf(best, M[m] + Vl[m * 12 + p]);
        V = best;
      } else {
        float cand[R]; float mx = -3.0e38f;
        #pragma unroll
        for (int m = 0; m < R; ++m) {
          cand[m] = M[m] + Vl[m * 12 + p];
          mx = fmaxf(mx, cand[m]);
        }
        float sum = 0.f;
        #pragma unroll
        for (int m = 0; m < R; ++m) sum += __expf(cand[m] - mx);
        V = mx + __logf(sum);
      }
    }
    __syncthreads();
  }
  if (act) {
    if (sem == 0) {
      ws[dstV  + s * 144 + n * 12 + p] = V;
      ws[dstVT + s * 144 + p * 12 + n] = V;
    } else {
      ws[dstF + s * 144 + n * 12 + p] = V;
    }
  }
}

// ---------------- K_midexpA: gold + hyper scans + expandA (1 block) ---------
// waves 0-2: mid scans (Viterbi fwd / Viterbi sfx / LSE fwd, depth 8);
// wave 3: gold reduce. __syncthreads. out[0]; expandA: 16 tasks x 16 lanes
// (tid<128 dir0, tid>=128 dir1). HBV/HSFX via LDS.
__global__ __launch_bounds__(256) void k_midexpA(
    const float* __restrict__ trans, float* __restrict__ ws,
    float* __restrict__ out)
{
  __shared__ float hbv_sh[NHYP][12];
  __shared__ float hsfx_sh[NHYP][12];
  __shared__ float Vm[3][16];
  __shared__ float VexA[16][16];
  __shared__ float gold_sh, lse_sh;

  int tid  = threadIdx.x;
  int wid  = tid >> 6;
  int lane = tid & 63;

  if (wid == 0) {
    // Viterbi forward -> hbv_sh + path_score
    int n = lane; bool act = (n < R);
    float x = -3.0e38f;
    if (act) {
      x = trans[n * NTAGS + T_START] + ws[OFF_FEATS + n];
      hbv_sh[0][n] = x;
      Vm[0][n] = x;
    }
    float row[R], rown[R];
    if (act) load12(ws + OFF_HMV + n * 12, row);
    for (int h = 0; h < NHYP; ++h) {
      if (act) load12(ws + OFF_HMV + (h + 1) * 144 + n * 12, rown); // h=7: HMVT, unused
      float v[R];
      lds12(Vm[0], v);
      if (act) {
        float nx = row[0] + v[0];
        #pragma unroll
        for (int m = 1; m < R; ++m) nx = fmaxf(nx, row[m] + v[m]);
        if (h < NHYP - 1) hbv_sh[h + 1][n] = nx;
        Vm[0][n] = nx;
        #pragma unroll
        for (int m = 0; m < R; ++m) row[m] = rown[m];
      }
    }
    if (lane == 0) {
      float v[R];
      lds12(Vm[0], v);
      float ps = -3.0e38f;
      #pragma unroll
      for (int m = 0; m < R; ++m) ps = fmaxf(ps, v[m] + trans[T_STOP * NTAGS + m]);
      out[1] = ps;
    }
  } else if (wid == 1) {
    // Viterbi suffix -> hsfx_sh
    int n = lane; bool act = (n < R);
    float x = -3.0e38f;
    if (act) {
      x = trans[T_STOP * NTAGS + n];
      hsfx_sh[NHYP - 1][n] = x;
      Vm[1][n] = x;
    }
    float row[R], rown[R];
    if (act) load12(ws + OFF_HMVT + (NHYP - 1) * 144 + n * 12, row);
    for (int h = NHYP - 1; h >= 1; --h) {
      if (act) load12(ws + OFF_HMVT + (h - 1) * 144 + n * 12, rown);
      float v[R];
      lds12(Vm[1], v);
      if (act) {
        float nx = row[0] + v[0];
        #pragma unroll
        for (int m = 1; m < R; ++m) nx = fmaxf(nx, row[m] + v[m]);
        hsfx_sh[h - 1][n] = nx;
        Vm[1][n] = nx;
        #pragma unroll
        for (int m = 0; m < R; ++m) row[m] = rown[m];
      }
    }
  } else if (wid == 2) {
    // LSE forward -> lse_sh
    int n = lane; bool act = (n < R);
    float x = -3.0e38f;
    if (act) {
      x = trans[n * NTAGS + T_START] + ws[OFF_FEATS + n];
      Vm[2][n] = x;
    }
    float row[R], rown[R];
    if (act) load12(ws + OFF_HMF + n * 12, row);
    for (int h = 0; h < NHYP; ++h) {
      if (act) load12(ws + OFF_HMF + (h + 1) * 144 + n * 12, rown); // h=7: SBV, unused
      float v[R];
      lds12(Vm[2], v);
      if (act) {
        float tv[R]; float mx = -3.0e38f;
        #pragma unroll
        for (int m = 0; m < R; ++m) { tv[m] = row[m] + v[m]; mx = fmaxf(mx, tv[m]); }
        float sum = 0.f;
        #pragma unroll
        for (int m = 0; m < R; ++m) sum += __expf(tv[m] - mx);
        Vm[2][n] = mx + __logf(sum);
        #pragma unroll
        for (int m = 0; m < R; ++m) row[m] = rown[m];
      }
    }
    if (lane == 0) {
      float v[R];
      lds12(Vm[2], v);
      float mx = -3.0e38f;
      #pragma unroll
      for (int m = 0; m < R; ++m) mx = fmaxf(mx, v[m] + trans[T_STOP * NTAGS + m]);
      float sum = 0.f;
      #pragma unroll
      for (int m = 0; m < R; ++m) sum += __expf(v[m] + trans[T_STOP * NTAGS + m] - mx);
      lse_sh = mx + __logf(sum);
    }
  } else {
    // gold reduce over 2048 partials
    float s = 0.f;
    for (int i = lane; i < CCH; i += 64) s += ws[OFF_GOLDP + i];
    #pragma unroll
    for (int off = 32; off > 0; off >>= 1) s += __shfl_xor(s, off);
    if (lane == 0) gold_sh = s;
  }
  __syncthreads();

  if (tid == 0) out[0] = lse_sh - gold_sh;

  // expandA: hyper vectors -> super vectors (SBV/SSFX to ws for k_expBdec)
  {
    int dir  = tid >> 7;          // waves 0-1: dir0, waves 2-3: dir1
    int h    = (tid >> 4) & 7;
    int g    = tid & 15;
    int task = tid >> 4;
    bool act = (g < R);

    if (dir == 0) {
      float x = -3.0e38f;
      if (act) {
        x = hbv_sh[h][g];
        ws[OFF_SBV + (h * 16) * 12 + g] = x;
        VexA[task][g] = x;
      }
      float row[R], rown[R];
      if (act) load12(ws + OFF_SMV + (h * 16) * 144 + g * 12, row);
      for (int j = 0; j < 15; ++j) {
        int s = h * 16 + j;
        if (act) load12(ws + OFF_SMV + (s + 1) * 144 + g * 12, rown);
        float v[R];
        lds12(VexA[task], v);
        if (act) {
          float nx = row[0] + v[0];
          #pragma unroll
          for (int m = 1; m < R; ++m) nx = fmaxf(nx, row[m] + v[m]);
          ws[OFF_SBV + (s + 1) * 12 + g] = nx;
          VexA[task][g] = nx;
          #pragma unroll
          for (int m = 0; m < R; ++m) row[m] = rown[m];
        }
      }
    } else {
      float x = -3.0e38f;
      if (act) {
        x = hsfx_sh[h][g];
        ws[OFF_SSFX + (h * 16 + 15) * 12 + g] = x;
        VexA[task][g] = x;
      }
      float row[R], rown[R];
      if (act) load12(ws + OFF_SMVT + (h * 16 + 15) * 144 + g * 12, row);
      for (int j = 15; j >= 1; --j) {
        int s = h * 16 + j;
        if (act) load12(ws + OFF_SMVT + (s - 1) * 144 + g * 12, rown);
        float v[R];
        lds12(VexA[task], v);
        if (act) {
          float nx = row[0] + v[0];
          #pragma unroll
          for (int m = 1; m < R; ++m) nx = fmaxf(nx, row[m] + v[m]);
          ws[OFF_SSFX + (s - 1) * 12 + g] = nx;
          VexA[task][g] = nx;
          #pragma unroll
          for (int m = 0; m < R; ++m) row[m] = rown[m];
        }
      }
    }
  }
}

// ---------------- K_expBdec: per-super expandB scans + decode ---------------
// 128 blocks x 256 thr. Phase A: wave0 lanes 0-15 compute BV for the super's
// 16 chunks (LDS); wave1 lanes 0-15 compute SFX. Phase B: decode 16 chunks
// x 16 lanes. No BV/SFX global round-trip.
__global__ __launch_bounds__(256) void k_expBdec(
    const float* __restrict__ trans, const float* __restrict__ ws,
    float* __restrict__ out)
{
  __shared__ float bv_sh[SCH][12];
  __shared__ float sfx_sh[SCH][12];
  __shared__ float Vdec[SCH][16];
  __shared__ unsigned char bpd[SCH][SCH][16];

  int tid = threadIdx.x;
  int s   = blockIdx.x;

  if (tid < 16) {
    // dir0: BV scan over PV mats
    int g = tid; bool act = (g < R);
    float x = -3.0e38f;
    if (act) { x = ws[OFF_SBV + s * 12 + g]; bv_sh[0][g] = x; }
    float row[R], rown[R];
    if (act) load12(ws + OFF_PV + (s * 16) * 144 + g * 12, row);
    for (int j = 0; j < 15; ++j) {
      if (act) load12(ws + OFF_PV + (s * 16 + j + 1) * 144 + g * 12, rown);
      float v[R];
      lds12(bv_sh[j], v);
      if (act) {
        float nx = row[0] + v[0];
        #pragma unroll
        for (int m = 1; m < R; ++m) nx = fmaxf(nx, row[m] + v[m]);
        bv_sh[j + 1][g] = nx;
        #pragma unroll
        for (int m = 0; m < R; ++m) row[m] = rown[m];
      }
    }
  } else if (tid >= 64 && tid < 80) {
    // dir1: SFX scan over PVC mats
    int g = tid - 64; bool act = (g < R);
    float x = -3.0e38f;
    if (act) { x = ws[OFF_SSFX + s * 12 + g]; sfx_sh[SCH - 1][g] = x; }
    float row[R], rown[R];
    if (act) load12(ws + OFF_PVC + (s * 16 + 15) * 144 + g * 12, row);
    for (int j = 15; j >= 1; --j) {
      if (act) load12(ws + OFF_PVC + (s * 16 + j - 1) * 144 + g * 12, rown);
      float v[R];
      lds12(sfx_sh[j], v);
      if (act) {
        float nx = row[0] + v[0];
        #pragma unroll
        for (int m = 1; m < R; ++m) nx = fmaxf(nx, row[m] + v[m]);
        sfx_sh[j - 1][g] = nx;
        #pragma unroll
        for (int m = 0; m < R; ++m) row[m] = rown[m];
      }
    }
  }
  __syncthreads();

  // decode: 16 chunks x 16 lanes
  {
    int q = tid >> 4;
    int g = tid & 15;
    int c = s * 16 + q;
    int t0 = (c == 0) ? 1 : c * SCH;
    int t1 = c * SCH + SCH;
    bool act = (g < R);

    float treg[R];
    #pragma unroll
    for (int m = 0; m < R; ++m) treg[m] = act ? trans[g * NTAGS + m] : 0.f;

    float fv = act ? bv_sh[q][g] : -3.0e38f;
    Vdec[q][g] = fv;
    float fc = ws[OFF_FEATS + t0 * 12 + g];

    for (int t = t0; t < t1; ++t) {
      float fn = ws[OFF_FEATS + (t + 1) * 12 + g];   // off-end: EXPF, unused
      float v[R];
      lds12(Vdec[q], v);
      float best = -3.0e38f; int bi = 0;
      #pragma unroll
      for (int m = 0; m < R; ++m) {
        float cand = treg[m] + v[m];
        if (cand > best) { best = cand; bi = m; }
      }
      float nfv = best + fc;
      if (act) {
        bpd[q][t - t0][g] = (unsigned char)bi;
        Vdec[q][g] = nfv;
      }
      fc = fn;
    }

    Vdec[q][g] = act ? (Vdec[q][g] + sfx_sh[q][g]) : -3.0e38f;

    if (g == 0) {
      float best = Vdec[q][0]; int idx = 0;
      #pragma unroll
      for (int m = 1; m < R; ++m) {
        float v = Vdec[q][m];
        if (v > best) { best = v; idx = m; }
      }
      int cur = idx;
      int len = t1 - t0;
      out[2 + t0 + len - 1] = (float)cur;
      for (int tt = len - 1; tt >= 1; --tt) {
        cur = bpd[q][tt][cur];
        out[2 + t0 + tt - 1] = (float)cur;
      }
      if (c == 0) {
        cur = bpd[q][0][cur];
        out[2 + 0] = (float)cur;
      }
    }
  }
}

extern "C" void kernel_launch(void* const* d_in, const int* in_sizes, int n_in,
                              void* d_out, int out_size, void* d_ws, size_t ws_size,
                              hipStream_t stream) {
  (void)in_sizes; (void)n_in; (void)out_size; (void)ws_size;
  const int*   sentence = (const int*)d_in[0];
  const int*   tags     = (const int*)d_in[1];
  const float* emb      = (const float*)d_in[2];
  const float* W        = (const float*)d_in[3];
  const float* trans    = (const float*)d_in[4];
  float* ws  = (float*)d_ws;
  float* out = (float*)d_out;

  k_feats<<<LSEQ / 16, 256, 0, stream>>>(sentence, tags, emb, W, trans, ws);
  k_pass1f<<<NSUP * 2, 256, 0, stream>>>(trans, ws);
  k_foldS<<<NHYP * 2, 192, 0, stream>>>(ws, OFF_SMV, OFF_SMF, OFF_HMV, OFF_HMVT, OFF_HMF);
  k_midexpA<<<1, 256, 0, stream>>>(trans, ws, out);
  k_expBdec<<<NSUP, 256, 0, stream>>>(trans, ws, out);
}

// Round 8
// 239.358 us; speedup vs baseline: 1.1584x; 1.0031x over previous
//
#include <hip/hip_runtime.h>

// EmbeddingCRF: feats = emb[sentence] @ W^T; CRF forward (LSE), gold score,
// Viterbi decode. Parallel-in-time via 12x12 semiring transfer matrices.
// Calibrated (R5-R11): grid.sync ~31us (dead); dispatch ~6us; serial semiring
// step ~0.4us when its input load is a cross-XCD global (~500-900cy exposed);
// single-block latency stacking ruinous (R10). Structure (R11, 240us):
//   k_feats | k_pass1f (pass1+fold1 fused) | k_foldS (fold2, 16 blocks) |
//   k_midexpA (hyper scans + expandA, 1 block) | k_expBdec (BV/SFX + decode).
// R12: kill the remaining exposed global latency in the serial scans by
// bulk-staging their (state-independent) inputs into LDS up front:
//   pass1f: block's EXPF/FEATS+FMAX range (13KB); midexpA: SMV+SMVT (147KB,
//   R9 proved large static LDS works); expBdec: super's PV+PVC+FEATS (31KB).
// Scan math unchanged; off-end prefetch hacks removed.

#define LSEQ    32768
#define NTAGS   14
#define R       12
#define T_START 12
#define T_STOP  13
#define EMBD    300
#define CCH     2048  // chunks
#define SCH     16    // steps per chunk
#define NSUP    128   // supers (16 chunks each)
#define NHYP    8     // hypers (16 supers each)

// ws layout (float offsets)
#define OFF_FEATS 0         // [L][12]
#define OFF_EXPF  393216    // [L][12]
#define OFF_FMAX  786432    // [L]
#define OFF_PV    1114112   // [2048][n][p] max-plus chunk mats
#define OFF_PVC   1409024   // [2048][p][n] transposed
#define OFF_SMV   1753104   // [128][n][p]
#define OFF_SMVT  1771536   // [128][p][n]
#define OFF_SMF   1789968   // [128][n][p]
#define OFF_HMV   1808400   // [8][n][p]
#define OFF_HMVT  1809552   // [8][p][n]
#define OFF_HMF   1810704   // [8][n][p]
#define OFF_SBV   1811856   // [128][12]
#define OFF_SSFX  1813392   // [128][12]
#define OFF_GOLDP 1815120   // [2048] per-block gold partials

__device__ __forceinline__ void load12(const float* __restrict__ p, float* r) {
  const float4* p4 = (const float4*)p;
  float4 a = p4[0], b = p4[1], c = p4[2];
  r[0]=a.x; r[1]=a.y; r[2]=a.z; r[3]=a.w;
  r[4]=b.x; r[5]=b.y; r[6]=b.z; r[7]=b.w;
  r[8]=c.x; r[9]=c.y; r[10]=c.z; r[11]=c.w;
}

__device__ __forceinline__ void lds12(const float* p, float* r) {
  const float4* p4 = (const float4*)p;
  float4 a = p4[0], b = p4[1], c = p4[2];
  r[0]=a.x; r[1]=a.y; r[2]=a.z; r[3]=a.w;
  r[4]=b.x; r[5]=b.y; r[6]=b.z; r[7]=b.w;
  r[8]=c.x; r[9]=c.y; r[10]=c.z; r[11]=c.w;
}

// ---------------- K1: feats + expfeat + featmax + gold partials -------------
__global__ __launch_bounds__(256) void k_feats(
    const int* __restrict__ sentence, const int* __restrict__ tags,
    const float* __restrict__ emb, const float* __restrict__ W,
    const float* __restrict__ trans, float* __restrict__ ws)
{
  __shared__ float Wl[NTAGS * EMBD];
  __shared__ float gacc;
  for (int i = threadIdx.x; i < NTAGS * EMBD; i += 256) Wl[i] = W[i];
  if (threadIdx.x == 0) gacc = 0.f;
  __syncthreads();

  int grp = threadIdx.x >> 4;
  int g   = threadIdx.x & 15;
  int pos = blockIdx.x * 16 + grp;
  int row = sentence[pos];

  float acc = 0.f;
  if (g < R) {
    const float4* e4 = (const float4*)(emb + (size_t)row * EMBD);
    const float4* w4 = (const float4*)(Wl + g * EMBD);
    #pragma unroll 5
    for (int i = 0; i < EMBD / 4; ++i) {
      float4 a = e4[i]; float4 b = w4[i];
      acc += a.x*b.x + a.y*b.y + a.z*b.z + a.w*b.w;
    }
  }
  float feat = (g < R) ? acc : -3.0e38f;
  float mx = feat;
  #pragma unroll
  for (int off = 1; off < 16; off <<= 1)
    mx = fmaxf(mx, __shfl_xor(mx, off, 16));

  if (g < R) {
    ws[OFF_FEATS + pos * 12 + g] = feat;
    ws[OFF_EXPF  + pos * 12 + g] = __expf(feat - mx);
  }
  if (g == 0) ws[OFF_FMAX + pos] = mx;

  int tg = tags[pos];
  if (g == tg) {
    int prev = (pos == 0) ? T_START : tags[pos - 1];
    float gc = feat + trans[tg * NTAGS + prev];
    if (pos == LSEQ - 1) gc += trans[T_STOP * NTAGS + tg];
    atomicAdd(&gacc, gc);
  }
  __syncthreads();
  if (threadIdx.x == 0) ws[OFF_GOLDP + blockIdx.x] = gacc;
}

// ---------------- K2: chunk transfer matrices + in-block fold1 --------------
// grid 256 = 128 supers x 2 semirings (sem = bid>>7: 0 LSE, 1 viterbi).
// block 256 thr = 16 chunks x 16 cols. P-1: stage block's EXPF/FEATS (+FMAX)
// range into LDS (13KB burst — removes per-step exposed global latency).
// Phase A: per-thread 16-step chunk scan from LDS; viterbi mats -> PV+PVC+LDS.
// Phase B: threads 0..143 fold 16 LDS mats -> super mat (SMF / SMV+SMVT).
// __launch_bounds__(256,1): allow ~200 VGPR, no spill (R5 trap).
__global__ __launch_bounds__(256, 1) void k_pass1f(
    const float* __restrict__ trans, float* __restrict__ ws)
{
  __shared__ float Fsh[256 * 12];   // 12 KB: EXPF (sem0) or FEATS (sem1)
  __shared__ float Xsh[256];        // FMAX (sem0 only)
  __shared__ float Msh[16 * 144];   // 9.2 KB
  __shared__ float Vl[144];

  int tid = threadIdx.x;
  int sem = blockIdx.x >> 7;
  int s   = blockIdx.x & 127;
  int q = tid >> 4;
  int p = tid & 15;
  int c = s * 16 + q;
  int t0 = (c == 0) ? 1 : c * SCH;
  int t1 = c * SCH + SCH;
  bool act = (p < R);

  // P-1: stage
  {
    int fbase = sem ? OFF_FEATS : OFF_EXPF;
    const float4* f4 = (const float4*)(ws + fbase + s * 256 * 12);
    float4* d4 = (float4*)Fsh;
    #pragma unroll
    for (int i = 0; i < 3; ++i) d4[tid + i * 256] = f4[tid + i * 256];
    if (sem == 0 && tid < 64) {
      const float4* x4 = (const float4*)(ws + OFF_FMAX + s * 256);
      ((float4*)Xsh)[tid] = x4[tid];
    }
  }
  __syncthreads();

  float Treg[R][R];

  if (sem == 0) {
    // LSE semiring (prob domain with exponent rescaling)
    #pragma unroll
    for (int n = 0; n < R; ++n)
      #pragma unroll
      for (int m = 0; m < R; ++m)
        Treg[n][m] = __expf(trans[n * NTAGS + m]);

    float E[R];
    #pragma unroll
    for (int m = 0; m < R; ++m) E[m] = (m == p) ? 1.f : 0.f;
    int kacc = 0;
    float sfeat = 0.f;

    for (int t = t0; t < t1; ++t) {
      int lt = t - s * 256;
      float ef[R];
      lds12(Fsh + lt * 12, ef);
      sfeat += Xsh[lt];
      float NE[R];
      #pragma unroll
      for (int n = 0; n < R; ++n) {
        float sv = Treg[n][0] * E[0];
        #pragma unroll
        for (int m = 1; m < R; ++m) sv = fmaf(Treg[n][m], E[m], sv);
        NE[n] = sv * ef[n];
      }
      #pragma unroll
      for (int n = 0; n < R; ++n) E[n] = NE[n];
      if ((t & 7) == 7) {
        float mx = E[0];
        #pragma unroll
        for (int n = 1; n < R; ++n) mx = fmaxf(mx, E[n]);
        if (mx > 0.f) {
          int k = ((__float_as_int(mx) >> 23) & 0xFF) - 127;
          float sc = __int_as_float((127 - k) << 23);
          #pragma unroll
          for (int n = 0; n < R; ++n) E[n] *= sc;
          kacc += k;
        }
      }
    }
    if (act) {
      float base = (float)kacc * 0.6931471805599453f + sfeat;
      #pragma unroll
      for (int n = 0; n < R; ++n) {
        float v = (E[n] > 0.f) ? (__logf(E[n]) + base) : -1.0e30f;
        Msh[q * 144 + n * 12 + p] = v;
      }
    }
  } else {
    // max-plus semiring
    #pragma unroll
    for (int n = 0; n < R; ++n)
      #pragma unroll
      for (int m = 0; m < R; ++m)
        Treg[n][m] = trans[n * NTAGS + m];

    float V[R];
    #pragma unroll
    for (int m = 0; m < R; ++m) V[m] = (m == p) ? 0.f : -1.0e30f;

    for (int t = t0; t < t1; ++t) {
      int lt = t - s * 256;
      float fr[R];
      lds12(Fsh + lt * 12, fr);
      float NV[R];
      #pragma unroll
      for (int n = 0; n < R; ++n) {
        float b = Treg[n][0] + V[0];
        #pragma unroll
        for (int m = 1; m < R; ++m) b = fmaxf(b, Treg[n][m] + V[m]);
        NV[n] = b + fr[n];
      }
      #pragma unroll
      for (int n = 0; n < R; ++n) V[n] = NV[n];
    }
    if (act) {
      #pragma unroll
      for (int n = 0; n < R; ++n) {
        ws[OFF_PV  + c * 144 + n * 12 + p] = V[n];
        ws[OFF_PVC + c * 144 + p * 12 + n] = V[n];
        Msh[q * 144 + n * 12 + p] = V[n];
      }
    }
  }
  __syncthreads();

  // Phase B: fold 16 chunk mats (LDS) -> super mat
  {
    int l = tid;
    bool fa = (l < 144);
    int fn = l / 12;
    int fp = l - fn * 12;
    float V = (fa && fn == fp) ? 0.f : -1.0e30f;

    for (int j = 0; j < 16; ++j) {
      if (fa) Vl[l] = V;
      __syncthreads();
      if (fa) {
        const float* M = Msh + j * 144 + fn * 12;
        if (sem == 1) {
          float best = -3.0e38f;
          #pragma unroll
          for (int m = 0; m < R; ++m)
            best = fmaxf(best, M[m] + Vl[m * 12 + fp]);
          V = best;
        } else {
          float cand[R]; float mx = -3.0e38f;
          #pragma unroll
          for (int m = 0; m < R; ++m) {
            cand[m] = M[m] + Vl[m * 12 + fp];
            mx = fmaxf(mx, cand[m]);
          }
          float sum = 0.f;
          #pragma unroll
          for (int m = 0; m < R; ++m) sum += __expf(cand[m] - mx);
          V = mx + __logf(sum);
        }
      }
      __syncthreads();
    }
    if (fa) {
      if (sem == 1) {
        ws[OFF_SMV  + s * 144 + fn * 12 + fp] = V;
        ws[OFF_SMVT + s * 144 + fp * 12 + fn] = V;
      } else {
        ws[OFF_SMF + s * 144 + fn * 12 + fp] = V;
      }
    }
  }
}

// ---------------- K_foldS: 16-way semiring fold, LDS-staged (fold2) ---------
// grid = NHYP*2; blockIdx&1: 0 = viterbi (SMV -> HMV+HMVT), 1 = LSE.
__global__ __launch_bounds__(192) void k_foldS(
    float* __restrict__ ws, int srcV, int srcF, int dstV, int dstVT, int dstF)
{
  __shared__ float Msh[16 * 144];   // 9.2 KB
  __shared__ float Vl[144];
  int s   = blockIdx.x >> 1;
  int sem = blockIdx.x & 1;
  int l = threadIdx.x;
  bool act = (l < 144);
  int n = l / 12;
  int p = l - n * 12;
  int base = sem ? srcF : srcV;

  // stage 16 mats = 2304 floats = 576 float4; 192 thr x 3
  const float4* src4 = (const float4*)(ws + base + s * (16 * 144));
  float4* d4 = (float4*)Msh;
  #pragma unroll
  for (int i = 0; i < 3; ++i) d4[l + i * 192] = src4[l + i * 192];

  float V = (act && n == p) ? 0.f : -1.0e30f;
  __syncthreads();

  for (int j = 0; j < 16; ++j) {
    if (act) Vl[l] = V;
    __syncthreads();
    if (act) {
      const float* M = Msh + j * 144 + n * 12;
      if (sem == 0) {
        float best = -3.0e38f;
        #pragma unroll
        for (int m = 0; m < R; ++m)
          best = fmaxf(best, M[m] + Vl[m * 12 + p]);
        V = best;
      } else {
        float cand[R]; float mx = -3.0e38f;
        #pragma unroll
        for (int m = 0; m < R; ++m) {
          cand[m] = M[m] + Vl[m * 12 + p];
          mx = fmaxf(mx, cand[m]);
        }
        float sum = 0.f;
        #pragma unroll
        for (int m = 0; m < R; ++m) sum += __expf(cand[m] - mx);
        V = mx + __logf(sum);
      }
    }
    __syncthreads();
  }
  if (act) {
    if (sem == 0) {
      ws[dstV  + s * 144 + n * 12 + p] = V;
      ws[dstVT + s * 144 + p * 12 + n] = V;
    } else {
      ws[dstF + s * 144 + n * 12 + p] = V;
    }
  }
}

// ---------------- K_midexpA: gold + hyper scans + expandA (1 block) ---------
// P-1: stage SMV+SMVT -> LDS (147KB; R9 proved large static LDS works).
// waves 0-2: mid scans (depth 8, global HMV/HMVT/HMF prefetched — tiny);
// wave 3: gold reduce. __syncthreads. out[0]; expandA: 16 tasks x 16 lanes
// from LDS (removes 15 x ~600cy exposed cross-XCD latency per task).
__global__ __launch_bounds__(256) void k_midexpA(
    const float* __restrict__ trans, float* __restrict__ ws,
    float* __restrict__ out)
{
  __shared__ float ssmv[NSUP * 144];    // 73728 B
  __shared__ float ssmvt[NSUP * 144];   // 73728 B
  __shared__ float hbv_sh[NHYP][12];
  __shared__ float hsfx_sh[NHYP][12];
  __shared__ float Vm[3][16];
  __shared__ float VexA[16][16];
  __shared__ float gold_sh, lse_sh;

  int tid  = threadIdx.x;
  int wid  = tid >> 6;
  int lane = tid & 63;

  // P-1: stage SMV + SMVT (loads drain while mid scans run; barrier below
  // covers the handoff to expandA)
  {
    const float4* a4 = (const float4*)(ws + OFF_SMV);
    const float4* b4 = (const float4*)(ws + OFF_SMVT);
    float4* d0 = (float4*)ssmv;
    float4* d1 = (float4*)ssmvt;
    for (int i = tid; i < NSUP * 36; i += 256) { d0[i] = a4[i]; d1[i] = b4[i]; }
  }

  if (wid == 0) {
    // Viterbi forward -> hbv_sh + path_score
    int n = lane; bool act = (n < R);
    float x = -3.0e38f;
    if (act) {
      x = trans[n * NTAGS + T_START] + ws[OFF_FEATS + n];
      hbv_sh[0][n] = x;
      Vm[0][n] = x;
    }
    float row[R], rown[R];
    if (act) load12(ws + OFF_HMV + n * 12, row);
    for (int h = 0; h < NHYP; ++h) {
      if (act) load12(ws + OFF_HMV + (h + 1) * 144 + n * 12, rown); // h=7: HMVT, unused
      float v[R];
      lds12(Vm[0], v);
      if (act) {
        float nx = row[0] + v[0];
        #pragma unroll
        for (int m = 1; m < R; ++m) nx = fmaxf(nx, row[m] + v[m]);
        if (h < NHYP - 1) hbv_sh[h + 1][n] = nx;
        Vm[0][n] = nx;
        #pragma unroll
        for (int m = 0; m < R; ++m) row[m] = rown[m];
      }
    }
    if (lane == 0) {
      float v[R];
      lds12(Vm[0], v);
      float ps = -3.0e38f;
      #pragma unroll
      for (int m = 0; m < R; ++m) ps = fmaxf(ps, v[m] + trans[T_STOP * NTAGS + m]);
      out[1] = ps;
    }
  } else if (wid == 1) {
    // Viterbi suffix -> hsfx_sh
    int n = lane; bool act = (n < R);
    float x = -3.0e38f;
    if (act) {
      x = trans[T_STOP * NTAGS + n];
      hsfx_sh[NHYP - 1][n] = x;
      Vm[1][n] = x;
    }
    float row[R], rown[R];
    if (act) load12(ws + OFF_HMVT + (NHYP - 1) * 144 + n * 12, row);
    for (int h = NHYP - 1; h >= 1; --h) {
      if (act) load12(ws + OFF_HMVT + (h - 1) * 144 + n * 12, rown);
      float v[R];
      lds12(Vm[1], v);
      if (act) {
        float nx = row[0] + v[0];
        #pragma unroll
        for (int m = 1; m < R; ++m) nx = fmaxf(nx, row[m] + v[m]);
        hsfx_sh[h - 1][n] = nx;
        Vm[1][n] = nx;
        #pragma unroll
        for (int m = 0; m < R; ++m) row[m] = rown[m];
      }
    }
  } else if (wid == 2) {
    // LSE forward -> lse_sh
    int n = lane; bool act = (n < R);
    float x = -3.0e38f;
    if (act) {
      x = trans[n * NTAGS + T_START] + ws[OFF_FEATS + n];
      Vm[2][n] = x;
    }
    float row[R], rown[R];
    if (act) load12(ws + OFF_HMF + n * 12, row);
    for (int h = 0; h < NHYP; ++h) {
      if (act) load12(ws + OFF_HMF + (h + 1) * 144 + n * 12, rown); // h=7: SBV, unused
      float v[R];
      lds12(Vm[2], v);
      if (act) {
        float tv[R]; float mx = -3.0e38f;
        #pragma unroll
        for (int m = 0; m < R; ++m) { tv[m] = row[m] + v[m]; mx = fmaxf(mx, tv[m]); }
        float sum = 0.f;
        #pragma unroll
        for (int m = 0; m < R; ++m) sum += __expf(tv[m] - mx);
        Vm[2][n] = mx + __logf(sum);
        #pragma unroll
        for (int m = 0; m < R; ++m) row[m] = rown[m];
      }
    }
    if (lane == 0) {
      float v[R];
      lds12(Vm[2], v);
      float mx = -3.0e38f;
      #pragma unroll
      for (int m = 0; m < R; ++m) mx = fmaxf(mx, v[m] + trans[T_STOP * NTAGS + m]);
      float sum = 0.f;
      #pragma unroll
      for (int m = 0; m < R; ++m) sum += __expf(v[m] + trans[T_STOP * NTAGS + m] - mx);
      lse_sh = mx + __logf(sum);
    }
  } else {
    // gold reduce over 2048 partials
    float s = 0.f;
    for (int i = lane; i < CCH; i += 64) s += ws[OFF_GOLDP + i];
    #pragma unroll
    for (int off = 32; off > 0; off >>= 1) s += __shfl_xor(s, off);
    if (lane == 0) gold_sh = s;
  }
  __syncthreads();

  if (tid == 0) out[0] = lse_sh - gold_sh;

  // expandA: hyper vectors -> super vectors (SBV/SSFX to ws), LDS-resident
  {
    int dir  = tid >> 7;          // waves 0-1: dir0, waves 2-3: dir1
    int h    = (tid >> 4) & 7;
    int g    = tid & 15;
    int task = tid >> 4;
    bool act = (g < R);

    if (dir == 0) {
      float x = -3.0e38f;
      if (act) {
        x = hbv_sh[h][g];
        ws[OFF_SBV + (h * 16) * 12 + g] = x;
        VexA[task][g] = x;
      }
      for (int j = 0; j < 15; ++j) {
        int s = h * 16 + j;
        float row[R], v[R];
        if (act) lds12(ssmv + s * 144 + g * 12, row);
        lds12(VexA[task], v);
        if (act) {
          float nx = row[0] + v[0];
          #pragma unroll
          for (int m = 1; m < R; ++m) nx = fmaxf(nx, row[m] + v[m]);
          ws[OFF_SBV + (s + 1) * 12 + g] = nx;
          VexA[task][g] = nx;
        }
      }
    } else {
      float x = -3.0e38f;
      if (act) {
        x = hsfx_sh[h][g];
        ws[OFF_SSFX + (h * 16 + 15) * 12 + g] = x;
        VexA[task][g] = x;
      }
      for (int j = 15; j >= 1; --j) {
        int s = h * 16 + j;
        float row[R], v[R];
        if (act) lds12(ssmvt + s * 144 + g * 12, row);
        lds12(VexA[task], v);
        if (act) {
          float nx = row[0] + v[0];
          #pragma unroll
          for (int m = 1; m < R; ++m) nx = fmaxf(nx, row[m] + v[m]);
          ws[OFF_SSFX + (s - 1) * 12 + g] = nx;
          VexA[task][g] = nx;
        }
      }
    }
  }
}

// ---------------- K_expBdec: per-super expandB scans + decode ---------------
// 128 blocks x 256 thr. P-1: stage super's PV+PVC (18KB) + FEATS range (12KB)
// into LDS with all 256 threads. Phase A: BV/SFX scans from LDS. Phase B:
// decode 16 chunks x 16 lanes from LDS.
__global__ __launch_bounds__(256) void k_expBdec(
    const float* __restrict__ trans, const float* __restrict__ ws,
    float* __restrict__ out)
{
  __shared__ float pv_sh[16 * 144];    // 9216 B
  __shared__ float pvc_sh[16 * 144];   // 9216 B
  __shared__ float f_sh[256 * 12];     // 12288 B
  __shared__ float bv_sh[SCH][12];
  __shared__ float sfx_sh[SCH][12];
  __shared__ float Vdec[SCH][16];
  __shared__ unsigned char bpd[SCH][SCH][16];

  int tid = threadIdx.x;
  int s   = blockIdx.x;

  // P-1: stage
  {
    const float4* a4 = (const float4*)(ws + OFF_PV  + s * (16 * 144));
    const float4* b4 = (const float4*)(ws + OFF_PVC + s * (16 * 144));
    const float4* c4 = (const float4*)(ws + OFF_FEATS + s * 256 * 12);
    float4* d0 = (float4*)pv_sh;
    float4* d1 = (float4*)pvc_sh;
    float4* d2 = (float4*)f_sh;
    #pragma unroll
    for (int i = 0; i < 2; ++i) {
      d0[tid + i * 256] = a4[tid + i * 256];
      d1[tid + i * 256] = b4[tid + i * 256];
    }
    if (tid < 64) { d0[tid + 512] = a4[tid + 512]; d1[tid + 512] = b4[tid + 512]; }
    #pragma unroll
    for (int i = 0; i < 3; ++i) d2[tid + i * 256] = c4[tid + i * 256];
  }
  __syncthreads();

  if (tid < 16) {
    // dir0: BV scan over PV mats (LDS)
    int g = tid; bool act = (g < R);
    float x = -3.0e38f;
    if (act) { x = ws[OFF_SBV + s * 12 + g]; bv_sh[0][g] = x; }
    for (int j = 0; j < 15; ++j) {
      float row[R], v[R];
      if (act) lds12(pv_sh + j * 144 + g * 12, row);
      lds12(bv_sh[j], v);
      if (act) {
        float nx = row[0] + v[0];
        #pragma unroll
        for (int m = 1; m < R; ++m) nx = fmaxf(nx, row[m] + v[m]);
        bv_sh[j + 1][g] = nx;
      }
    }
  } else if (tid >= 64 && tid < 80) {
    // dir1: SFX scan over PVC mats (LDS)
    int g = tid - 64; bool act = (g < R);
    float x = -3.0e38f;
    if (act) { x = ws[OFF_SSFX + s * 12 + g]; sfx_sh[SCH - 1][g] = x; }
    for (int j = 15; j >= 1; --j) {
      float row[R], v[R];
      if (act) lds12(pvc_sh + j * 144 + g * 12, row);
      lds12(sfx_sh[j], v);
      if (act) {
        float nx = row[0] + v[0];
        #pragma unroll
        for (int m = 1; m < R; ++m) nx = fmaxf(nx, row[m] + v[m]);
        sfx_sh[j - 1][g] = nx;
      }
    }
  }
  __syncthreads();

  // decode: 16 chunks x 16 lanes (FEATS from LDS)
  {
    int q = tid >> 4;
    int g = tid & 15;
    int c = s * 16 + q;
    int t0 = (c == 0) ? 1 : c * SCH;
    int t1 = c * SCH + SCH;
    bool act = (g < R);

    float treg[R];
    #pragma unroll
    for (int m = 0; m < R; ++m) treg[m] = act ? trans[g * NTAGS + m] : 0.f;

    float fv = act ? bv_sh[q][g] : -3.0e38f;
    Vdec[q][g] = fv;

    for (int t = t0; t < t1; ++t) {
      int lt = t - s * 256;
      float fc = f_sh[lt * 12 + g];
      float v[R];
      lds12(Vdec[q], v);
      float best = -3.0e38f; int bi = 0;
      #pragma unroll
      for (int m = 0; m < R; ++m) {
        float cand = treg[m] + v[m];
        if (cand > best) { best = cand; bi = m; }
      }
      float nfv = best + fc;
      if (act) {
        bpd[q][t - t0][g] = (unsigned char)bi;
        Vdec[q][g] = nfv;
      }
    }

    Vdec[q][g] = act ? (Vdec[q][g] + sfx_sh[q][g]) : -3.0e38f;

    if (g == 0) {
      float best = Vdec[q][0]; int idx = 0;
      #pragma unroll
      for (int m = 1; m < R; ++m) {
        float v = Vdec[q][m];
        if (v > best) { best = v; idx = m; }
      }
      int cur = idx;
      int len = t1 - t0;
      out[2 + t0 + len - 1] = (float)cur;
      for (int tt = len - 1; tt >= 1; --tt) {
        cur = bpd[q][tt][cur];
        out[2 + t0 + tt - 1] = (float)cur;
      }
      if (c == 0) {
        cur = bpd[q][0][cur];
        out[2 + 0] = (float)cur;
      }
    }
  }
}

extern "C" void kernel_launch(void* const* d_in, const int* in_sizes, int n_in,
                              void* d_out, int out_size, void* d_ws, size_t ws_size,
                              hipStream_t stream) {
  (void)in_sizes; (void)n_in; (void)out_size; (void)ws_size;
  const int*   sentence = (const int*)d_in[0];
  const int*   tags     = (const int*)d_in[1];
  const float* emb      = (const float*)d_in[2];
  const float* W        = (const float*)d_in[3];
  const float* trans    = (const float*)d_in[4];
  float* ws  = (float*)d_ws;
  float* out = (float*)d_out;

  k_feats<<<LSEQ / 16, 256, 0, stream>>>(sentence, tags, emb, W, trans, ws);
  k_pass1f<<<NSUP * 2, 256, 0, stream>>>(trans, ws);
  k_foldS<<<NHYP * 2, 192, 0, stream>>>(ws, OFF_SMV, OFF_SMF, OFF_HMV, OFF_HMVT, OFF_HMF);
  k_midexpA<<<1, 256, 0, stream>>>(trans, ws, out);
  k_expBdec<<<NSUP, 256, 0, stream>>>(trans, ws, out);
}